// Round 6
// baseline (206.600 us; speedup 1.0000x reference)
//
#include <hip/hip_runtime.h>
#include <hip/hip_bf16.h>

#define D_MODEL 1280
#define NUM_HEADS 16
#define D_K 80
#define DP 96            // head dim padded to 3*32 for MFMA K-steps
#define SEQ 1024
#define BATCH 4
#define BH (BATCH*NUM_HEADS)

typedef __hip_bfloat16 bf16;
typedef short short8 __attribute__((ext_vector_type(8)));
typedef short short4v __attribute__((ext_vector_type(4)));
typedef float f32x4 __attribute__((ext_vector_type(4)));

__device__ __forceinline__ float b2f(bf16 x) { return __bfloat162float(x); }
__device__ __forceinline__ bf16 f2b(float x) { return __float2bfloat16(x); }
__device__ __forceinline__ short bbits(float x) {
    union { bf16 b; short s; } u; u.b = __float2bfloat16(x); return u.s;
}

#define MFMA16(a, b, c) __builtin_amdgcn_mfma_f32_16x16x32_bf16(a, b, c, 0, 0, 0)

// ---------------------------------------------------------------------------
// Kernel 0 (merged): pack Wq|Wk|Wv -> Wcat[h][240][96] bf16 with the
// channel-shuffle permutation folded into the K(input)-dim: column e' of
// Wcat = original input j*5+c where c=e'/16, j=e'%16. Cols 80..95 zero.
// Also Wo fp32 -> bf16.
// ---------------------------------------------------------------------------
__global__ __launch_bounds__(256) void cvt_all_kernel(
    const float* __restrict__ Wq, const float* __restrict__ Wk,
    const float* __restrict__ Wv, bf16* __restrict__ Wcat,
    const float* __restrict__ Wo, bf16* __restrict__ Wb)
{
    if (blockIdx.x < 1440) {
        int idx = blockIdx.x * 256 + threadIdx.x;
        int col = idx % 96;
        int row = (idx / 96) % 240;
        int h   = idx / (96 * 240);
        int mat = row / 80, e = row % 80;
        int c = col >> 4, j = col & 15;          // e' = c*16 + j
        const float* W = (mat == 0) ? Wq : (mat == 1) ? Wk : Wv;
        float v = (col < 80) ? W[(size_t)(h * 80 + e) * 80 + (j * 5 + c)] : 0.f;
        Wcat[idx] = f2b(v);
    } else {
        int idx = ((blockIdx.x - 1440) * 256 + threadIdx.x) * 4;
        float4 v = *(const float4*)(Wo + idx);
        Wb[idx]     = f2b(v.x);
        Wb[idx + 1] = f2b(v.y);
        Wb[idx + 2] = f2b(v.z);
        Wb[idx + 3] = f2b(v.w);
    }
}

// ---------------------------------------------------------------------------
// Kernel 1: per-head QKV projection via MFMA, register-direct X fragments.
// (unchanged from round 4)
// ---------------------------------------------------------------------------
__global__ __launch_bounds__(256) void qkv_kernel(
    const float* __restrict__ src,
    const float* __restrict__ bq, const float* __restrict__ bk,
    const float* __restrict__ bv, const bf16* __restrict__ Wcat,
    bf16* __restrict__ Qb, bf16* __restrict__ Kb, bf16* __restrict__ Vg)
{
    const int h = blockIdx.y;
    const int b = blockIdx.x >> 3;
    const int s0 = (blockIdx.x & 7) * 128;
    const int tid = threadIdx.x;
    const int wave = tid >> 6, lane = tid & 63;
    const int lquad = lane >> 4, lcol = lane & 15;
    const int bh = b * NUM_HEADS + h;

    // X fragments straight from global (permuted-K ordering)
    short8 xf[2][3];
    #pragma unroll
    for (int mt = 0; mt < 2; mt++)
        #pragma unroll
        for (int ks = 0; ks < 3; ks++) {
            const int c  = 2 * ks + (lquad >> 1);
            const int j0 = (lquad & 1) * 8;
            short8 t = {0, 0, 0, 0, 0, 0, 0, 0};
            if (c < 5) {   // c==5 is the zero pad (W pad cols are zero too)
                const float* p = src
                    + (size_t)(b * SEQ + s0 + wave * 32 + mt * 16 + lcol) * D_MODEL
                    + c * 256 + h * 16 + j0;
                float4 v0 = *(const float4*)p;
                float4 v1 = *(const float4*)(p + 4);
                t[0] = bbits(v0.x); t[1] = bbits(v0.y);
                t[2] = bbits(v0.z); t[3] = bbits(v0.w);
                t[4] = bbits(v1.x); t[5] = bbits(v1.y);
                t[6] = bbits(v1.z); t[7] = bbits(v1.w);
            }
            xf[mt][ks] = t;
        }

    const bf16* Wh = Wcat + (size_t)h * 240 * 96;
    const float qscale = 1.4426950408889634f * 0.11180339887498949f;
    const f32x4 fzero = {0.f, 0.f, 0.f, 0.f};

    // ---- Q and K: D[token][e] ----
    #pragma unroll
    for (int mat = 0; mat < 2; mat++) {
        const bf16* Wm = Wh + mat * 80 * 96;
        short8 wf[5][3];
        #pragma unroll
        for (int n = 0; n < 5; n++)
            #pragma unroll
            for (int ks = 0; ks < 3; ks++)
                wf[n][ks] = *(const short8*)(Wm + (n*16 + lcol)*96 + ks*32 + lquad*8);

        f32x4 acc[2][5];
        #pragma unroll
        for (int n = 0; n < 5; n++) {          // first ks folds zero-init
            acc[0][n] = MFMA16(xf[0][0], wf[n][0], fzero);
            acc[1][n] = MFMA16(xf[1][0], wf[n][0], fzero);
        }
        #pragma unroll
        for (int ks = 1; ks < 3; ks++)
            #pragma unroll
            for (int n = 0; n < 5; n++) {
                acc[0][n] = MFMA16(xf[0][ks], wf[n][ks], acc[0][n]);
                acc[1][n] = MFMA16(xf[1][ks], wf[n][ks], acc[1][n]);
            }

        const float* bias = (mat == 0) ? bq : bk;
        bf16* Out = (mat == 0) ? Qb : Kb;
        const float scale = (mat == 0) ? qscale : 1.f;
        #pragma unroll
        for (int n = 0; n < 5; n++) {
            float bb = bias[h * 80 + n * 16 + lcol];
            #pragma unroll
            for (int mt = 0; mt < 2; mt++)
                #pragma unroll
                for (int r = 0; r < 4; r++) {
                    int srow = s0 + wave*32 + mt*16 + lquad*4 + r;
                    Out[((size_t)bh * SEQ + srow) * DP + n*16 + lcol] =
                        f2b((acc[mt][n][r] + bb) * scale);
                }
        }
    }
    // zero pad e = 80..95 for Q and K (128 rows, 256 threads)
    {
        int i = tid >> 1, half = tid & 1;
        size_t row = ((size_t)bh * SEQ + s0 + i) * DP + 80 + half * 8;
        *(uint4*)(Qb + row) = make_uint4(0, 0, 0, 0);
        *(uint4*)(Kb + row) = make_uint4(0, 0, 0, 0);
    }

    // ---- V: D[e][token] ----
    {
        const bf16* Wm = Wh + 2 * 80 * 96;
        short8 wf[5][3];
        #pragma unroll
        for (int m = 0; m < 5; m++)
            #pragma unroll
            for (int ks = 0; ks < 3; ks++)
                wf[m][ks] = *(const short8*)(Wm + (m*16 + lcol)*96 + ks*32 + lquad*8);

        f32x4 acc[5][2];
        #pragma unroll
        for (int m = 0; m < 5; m++) {          // first ks folds zero-init
            acc[m][0] = MFMA16(wf[m][0], xf[0][0], fzero);
            acc[m][1] = MFMA16(wf[m][0], xf[1][0], fzero);
        }
        #pragma unroll
        for (int ks = 1; ks < 3; ks++)
            #pragma unroll
            for (int m = 0; m < 5; m++) {
                acc[m][0] = MFMA16(wf[m][ks], xf[0][ks], acc[m][0]);
                acc[m][1] = MFMA16(wf[m][ks], xf[1][ks], acc[m][1]);
            }

        #pragma unroll
        for (int m = 0; m < 5; m++) {
            float4 bb4 = *(const float4*)(bv + h * 80 + m * 16 + lquad * 4);
            float bb[4] = {bb4.x, bb4.y, bb4.z, bb4.w};
            #pragma unroll
            for (int nt = 0; nt < 2; nt++)
                #pragma unroll
                for (int r = 0; r < 4; r++) {
                    int e = m*16 + lquad*4 + r;
                    int token = s0 + wave*32 + nt*16 + lcol;
                    Vg[((size_t)bh * D_K + e) * SEQ + token] =
                        f2b(acc[m][nt][r] + bb[r]);
                }
        }
    }
}

// ---------------------------------------------------------------------------
// Kernel 2: MFMA flash attention. Round-3 schedule (T14 K prefetch, 2 waves,
// grid-capped 4 blocks/CU) + V read per-lane from L2 with loads issued at the
// TOP of each iteration (QK^T+softmax ~600cy covers L2 latency; round-5's
// defect was issuing them right before PV). No Vt LDS: publish = 6 K writes.
// LDS 26,624 B: Qs/P 13312 | Ks 13312.
// ---------------------------------------------------------------------------
__global__ __launch_bounds__(128, 2) void attn_kernel(
    const bf16* __restrict__ Qb, const bf16* __restrict__ Kb,
    const bf16* __restrict__ Vg, bf16* __restrict__ Cc)
{
    __shared__ char smem[26624];
    bf16* Qs = (bf16*)smem;
    bf16* Ks = (bf16*)(smem + 13312);

    const int tid = threadIdx.x;
    const int wave = tid >> 6, lane = tid & 63;
    const int lquad = lane >> 4, lcol = lane & 15;
    const int bh = blockIdx.x;
    const int b = bh >> 4, h = bh & 15;
    const int q0 = blockIdx.y * 64;

    const uint4* Kg = (const uint4*)(Kb + (size_t)bh * SEQ * DP);
    // per-lane V row base: row = ne*16+lcol, chunk lquad*8 (verified r5)
    const bf16* Vl = Vg + ((size_t)bh * D_K + lcol) * SEQ + lquad * 8;

    // K staging map as individual scalars (NO arrays -> no scratch demotion)
    const int i0 = tid, i1 = tid + 128, i2 = tid + 256,
              i3 = tid + 384, i4 = tid + 512, i5 = tid + 640;
    const int kd0 = (i0/12)*104 + (i0%12)*8, kd1 = (i1/12)*104 + (i1%12)*8,
              kd2 = (i2/12)*104 + (i2%12)*8, kd3 = (i3/12)*104 + (i3%12)*8,
              kd4 = (i4/12)*104 + (i4%12)*8, kd5 = (i5/12)*104 + (i5%12)*8;

    // stage Q tile: 64 x 96 -> row stride 104
    {
        const uint4* qg = (const uint4*)(Qb + ((size_t)bh * SEQ + q0) * DP);
        #pragma unroll
        for (int i = 0; i < 6; i++) {
            int idx = tid + i * 128, r = idx / 12, c = idx % 12;
            *(uint4*)(Qs + r * 104 + c * 8) = qg[idx];
        }
    }
    __syncthreads();

    short8 qf[2][3];
    #pragma unroll
    for (int nt = 0; nt < 2; nt++)
        #pragma unroll
        for (int ks = 0; ks < 3; ks++)
            qf[nt][ks] = *(const short8*)(Qs + (wave*32 + nt*16 + lcol)*104 + ks*32 + lquad*8);

    // stage K tile 0 (Ks region; does not touch Qs)
    *(uint4*)(Ks + kd0) = Kg[i0];
    *(uint4*)(Ks + kd1) = Kg[i1];
    *(uint4*)(Ks + kd2) = Kg[i2];
    *(uint4*)(Ks + kd3) = Kg[i3];
    *(uint4*)(Ks + kd4) = Kg[i4];
    *(uint4*)(Ks + kd5) = Kg[i5];
    __syncthreads();   // tile 0 visible; all qf reads drained (P overlays Qs)

    f32x4 Oacc[2][5];
    #pragma unroll
    for (int mt = 0; mt < 2; mt++)
        #pragma unroll
        for (int ne = 0; ne < 5; ne++)
            #pragma unroll
            for (int r = 0; r < 4; r++) Oacc[mt][ne][r] = 0.f;

    f32x4 lsum4[2];
    #pragma unroll
    for (int nt = 0; nt < 2; nt++)
        #pragma unroll
        for (int r = 0; r < 4; r++) lsum4[nt][r] = 0.f;

    bf16* Pw = (bf16*)(smem + wave * 4608);   // per-wave 32 x 72 (overlays Qs)
    const f32x4 fzero = {0.f, 0.f, 0.f, 0.f};

    for (int kt = 0; kt < 16; kt++) {
        // V fragments for THIS tile issued FIRST (T14: ~600cy of QK^T+softmax
        // covers the L2 latency before PV consumes them)
        const bf16* Vk = Vl + kt * 64;
        short8 v00 = *(const short8*)(Vk);                     // js=0, ne=0
        short8 v01 = *(const short8*)(Vk + 16 * SEQ);          // js=0, ne=1
        short8 v02 = *(const short8*)(Vk + 32 * SEQ);
        short8 v03 = *(const short8*)(Vk + 48 * SEQ);
        short8 v04 = *(const short8*)(Vk + 64 * SEQ);
        short8 v10 = *(const short8*)(Vk + 32);                // js=1, ne=0
        short8 v11 = *(const short8*)(Vk + 16 * SEQ + 32);
        short8 v12 = *(const short8*)(Vk + 32 * SEQ + 32);
        short8 v13 = *(const short8*)(Vk + 48 * SEQ + 32);
        short8 v14 = *(const short8*)(Vk + 64 * SEQ + 32);

        // T14: next K tile's loads into scalar regs; straight-line CFG
        const int ktn = (kt + 1) & 15;          // last iter republishes tile 0
        uint4 kA = Kg[ktn * 768 + i0];
        uint4 kB = Kg[ktn * 768 + i1];
        uint4 kC = Kg[ktn * 768 + i2];
        uint4 kD = Kg[ktn * 768 + i3];
        uint4 kE = Kg[ktn * 768 + i4];
        uint4 kF = Kg[ktn * 768 + i5];

        // S^T = K·Q^T (first ks folds the zero-init)
        f32x4 st[4][2];
        __builtin_amdgcn_s_setprio(1);
        #pragma unroll
        for (int mt = 0; mt < 4; mt++) {
            short8 af = *(const short8*)(Ks + (mt*16 + lcol)*104 + lquad*8);
            st[mt][0] = MFMA16(af, qf[0][0], fzero);
            st[mt][1] = MFMA16(af, qf[1][0], fzero);
        }
        #pragma unroll
        for (int ks = 1; ks < 3; ks++)
            #pragma unroll
            for (int mt = 0; mt < 4; mt++) {
                short8 af = *(const short8*)(Ks + (mt*16 + lcol)*104 + ks*32 + lquad*8);
                st[mt][0] = MFMA16(af, qf[0][ks], st[mt][0]);
                st[mt][1] = MFMA16(af, qf[1][ks], st[mt][1]);
            }
        __builtin_amdgcn_s_setprio(0);

        // softmax numerator: p = exp2(s), vector lsum, packed P store
        #pragma unroll
        for (int nt = 0; nt < 2; nt++)
            #pragma unroll
            for (int mt = 0; mt < 4; mt++) {
                short4v pk;
                #pragma unroll
                for (int r = 0; r < 4; r++) {
                    float p = __builtin_amdgcn_exp2f(st[mt][nt][r]);
                    lsum4[nt][r] += p;
                    pk[r] = bbits(p);
                }
                *(short4v*)(Pw + (nt*16 + lcol)*72 + mt*16 + lquad*4) = pk;
            }

        // PV accumulate (Pw wave-private -> no barrier; V already in regs)
        __builtin_amdgcn_s_setprio(1);
        {
            short8 pf0 = *(const short8*)(Pw + lcol*72 + lquad*8);
            short8 pf1 = *(const short8*)(Pw + (16 + lcol)*72 + lquad*8);
            Oacc[0][0] = MFMA16(pf0, v00, Oacc[0][0]);
            Oacc[1][0] = MFMA16(pf1, v00, Oacc[1][0]);
            Oacc[0][1] = MFMA16(pf0, v01, Oacc[0][1]);
            Oacc[1][1] = MFMA16(pf1, v01, Oacc[1][1]);
            Oacc[0][2] = MFMA16(pf0, v02, Oacc[0][2]);
            Oacc[1][2] = MFMA16(pf1, v02, Oacc[1][2]);
            Oacc[0][3] = MFMA16(pf0, v03, Oacc[0][3]);
            Oacc[1][3] = MFMA16(pf1, v03, Oacc[1][3]);
            Oacc[0][4] = MFMA16(pf0, v04, Oacc[0][4]);
            Oacc[1][4] = MFMA16(pf1, v04, Oacc[1][4]);
        }
        {
            short8 pf0 = *(const short8*)(Pw + lcol*72 + 32 + lquad*8);
            short8 pf1 = *(const short8*)(Pw + (16 + lcol)*72 + 32 + lquad*8);
            Oacc[0][0] = MFMA16(pf0, v10, Oacc[0][0]);
            Oacc[1][0] = MFMA16(pf1, v10, Oacc[1][0]);
            Oacc[0][1] = MFMA16(pf0, v11, Oacc[0][1]);
            Oacc[1][1] = MFMA16(pf1, v11, Oacc[1][1]);
            Oacc[0][2] = MFMA16(pf0, v12, Oacc[0][2]);
            Oacc[1][2] = MFMA16(pf1, v12, Oacc[1][2]);
            Oacc[0][3] = MFMA16(pf0, v13, Oacc[0][3]);
            Oacc[1][3] = MFMA16(pf1, v13, Oacc[1][3]);
            Oacc[0][4] = MFMA16(pf0, v14, Oacc[0][4]);
            Oacc[1][4] = MFMA16(pf1, v14, Oacc[1][4]);
        }
        __builtin_amdgcn_s_setprio(0);

        // publish K tile kt+1: only 6 fast ds_writes between the barriers
        __syncthreads();
        *(uint4*)(Ks + kd0) = kA;
        *(uint4*)(Ks + kd1) = kB;
        *(uint4*)(Ks + kd2) = kC;
        *(uint4*)(Ks + kd3) = kD;
        *(uint4*)(Ks + kd4) = kE;
        *(uint4*)(Ks + kd5) = kF;
        __syncthreads();
    }

    // single l-reduce + normalize + write
    float inv[2];
    #pragma unroll
    for (int nt = 0; nt < 2; nt++) {
        float s = (lsum4[nt][0] + lsum4[nt][1]) + (lsum4[nt][2] + lsum4[nt][3]);
        s += __shfl_xor(s, 16);
        s += __shfl_xor(s, 32);
        inv[nt] = 1.f / s;
    }
    #pragma unroll
    for (int mt = 0; mt < 2; mt++) {
        f32x4 li;
        #pragma unroll
        for (int r = 0; r < 4; r++)
            li[r] = __shfl(inv[mt], (lane & 48) | (lquad*4 + r));
        #pragma unroll
        for (int ne = 0; ne < 5; ne++)
            #pragma unroll
            for (int r = 0; r < 4; r++) {
                int s_row = q0 + wave*32 + mt*16 + lquad*4 + r;
                int e = ne*16 + lcol;
                Cc[(size_t)(b * SEQ + s_row) * D_MODEL + h * D_K + e] =
                    f2b(Oacc[mt][ne][r] * li[r]);
            }
    }
}

// ---------------------------------------------------------------------------
// Kernel 3: output projection out = Cc @ Wo^T + bo via MFMA (unchanged r4).
// ---------------------------------------------------------------------------
__global__ __launch_bounds__(256) void proj_kernel(
    const bf16* __restrict__ Cc, const bf16* __restrict__ Wb,
    const float* __restrict__ bo, float* __restrict__ out)
{
    __shared__ bf16 As[128 * 72];
    __shared__ bf16 Bs[128 * 72];
    const int tid = threadIdx.x;
    const int wave = tid >> 6, lane = tid & 63;
    const int lquad = lane >> 4, lcol = lane & 15;
    const int t0 = blockIdx.x * 128, o0 = blockIdx.y * 128;
    const int mrow = (wave & 1) * 64, ncol = (wave >> 1) * 64;

    // staging maps as individual scalars
    const int i0 = tid, i1 = tid + 256, i2 = tid + 512, i3 = tid + 768;
    const int d0 = (i0>>3)*72 + (i0&7)*8, d1 = (i1>>3)*72 + (i1&7)*8,
              d2 = (i2>>3)*72 + (i2&7)*8, d3 = (i3>>3)*72 + (i3&7)*8;
    const size_t gA0 = (size_t)(t0 + (i0>>3))*D_MODEL + (i0&7)*8;
    const size_t gA1 = (size_t)(t0 + (i1>>3))*D_MODEL + (i1&7)*8;
    const size_t gA2 = (size_t)(t0 + (i2>>3))*D_MODEL + (i2&7)*8;
    const size_t gA3 = (size_t)(t0 + (i3>>3))*D_MODEL + (i3&7)*8;
    const size_t gB0 = (size_t)(o0 + (i0>>3))*D_MODEL + (i0&7)*8;
    const size_t gB1 = (size_t)(o0 + (i1>>3))*D_MODEL + (i1&7)*8;
    const size_t gB2 = (size_t)(o0 + (i2>>3))*D_MODEL + (i2&7)*8;
    const size_t gB3 = (size_t)(o0 + (i3>>3))*D_MODEL + (i3&7)*8;

    // stage K-chunk 0
    *(uint4*)(As + d0) = *(const uint4*)(Cc + gA0);
    *(uint4*)(As + d1) = *(const uint4*)(Cc + gA1);
    *(uint4*)(As + d2) = *(const uint4*)(Cc + gA2);
    *(uint4*)(As + d3) = *(const uint4*)(Cc + gA3);
    *(uint4*)(Bs + d0) = *(const uint4*)(Wb + gB0);
    *(uint4*)(Bs + d1) = *(const uint4*)(Wb + gB1);
    *(uint4*)(Bs + d2) = *(const uint4*)(Wb + gB2);
    *(uint4*)(Bs + d3) = *(const uint4*)(Wb + gB3);
    __syncthreads();

    f32x4 acc[4][4];
    #pragma unroll
    for (int mt = 0; mt < 4; mt++)
        #pragma unroll
        for (int nt = 0; nt < 4; nt++)
            #pragma unroll
            for (int r = 0; r < 4; r++) acc[mt][nt][r] = 0.f;

    for (int kc = 0; kc < 20; kc++) {
        // T14: prefetch next K-chunk into scalar regs (wraps to 0 at end)
        const int kn = (kc < 19) ? (kc + 1) * 64 : 0;
        uint4 pa0 = *(const uint4*)(Cc + gA0 + kn);
        uint4 pa1 = *(const uint4*)(Cc + gA1 + kn);
        uint4 pa2 = *(const uint4*)(Cc + gA2 + kn);
        uint4 pa3 = *(const uint4*)(Cc + gA3 + kn);
        uint4 pb0 = *(const uint4*)(Wb + gB0 + kn);
        uint4 pb1 = *(const uint4*)(Wb + gB1 + kn);
        uint4 pb2 = *(const uint4*)(Wb + gB2 + kn);
        uint4 pb3 = *(const uint4*)(Wb + gB3 + kn);

        __builtin_amdgcn_s_setprio(1);
        #pragma unroll
        for (int ks = 0; ks < 2; ks++) {
            short8 am[4], bn[4];
            #pragma unroll
            for (int t = 0; t < 4; t++) {
                am[t] = *(const short8*)(As + (mrow + t*16 + lcol)*72 + ks*32 + lquad*8);
                bn[t] = *(const short8*)(Bs + (ncol + t*16 + lcol)*72 + ks*32 + lquad*8);
            }
            #pragma unroll
            for (int mt = 0; mt < 4; mt++)
                #pragma unroll
                for (int nt = 0; nt < 4; nt++)
                    acc[mt][nt] = MFMA16(am[mt], bn[nt], acc[mt][nt]);
        }
        __builtin_amdgcn_s_setprio(0);

        // publish: only fast ds_writes between the barriers
        __syncthreads();
        *(uint4*)(As + d0) = pa0;
        *(uint4*)(As + d1) = pa1;
        *(uint4*)(As + d2) = pa2;
        *(uint4*)(As + d3) = pa3;
        *(uint4*)(Bs + d0) = pb0;
        *(uint4*)(Bs + d1) = pb1;
        *(uint4*)(Bs + d2) = pb2;
        *(uint4*)(Bs + d3) = pb3;
        __syncthreads();
    }

    #pragma unroll
    for (int nt = 0; nt < 4; nt++) {
        float bias = bo[o0 + ncol + nt*16 + lcol];
        #pragma unroll
        for (int mt = 0; mt < 4; mt++)
            #pragma unroll
            for (int r = 0; r < 4; r++)
                out[(size_t)(t0 + mrow + mt*16 + lquad*4 + r) * D_MODEL
                    + o0 + ncol + nt*16 + lcol] = acc[mt][nt][r] + bias;
    }
}

// ---------------------------------------------------------------------------
extern "C" void kernel_launch(void* const* d_in, const int* in_sizes, int n_in,
                              void* d_out, int out_size, void* d_ws, size_t ws_size,
                              hipStream_t stream) {
    const float* src = (const float*)d_in[0];
    const float* Wq = (const float*)d_in[3];
    const float* bq = (const float*)d_in[4];
    const float* Wk = (const float*)d_in[5];
    const float* bk = (const float*)d_in[6];
    const float* Wv = (const float*)d_in[7];
    const float* bv = (const float*)d_in[8];
    const float* Wo = (const float*)d_in[9];
    const float* bo = (const float*)d_in[10];
    float* out = (float*)d_out;

    // ws layout (bytes):
    //   Qb bf16 [BH][S][96]    @ 0         12,582,912
    //   Kb bf16 [BH][S][96]    @ 12582912  12,582,912
    //   Vg bf16 [BH][80][S]    @ 25165824  10,485,760
    //   Cc bf16 [B][S][1280]   @ 35651584  10,485,760  (also Wcat before attn)
    //   Wb bf16 [1280][1280]   @ 46137344   3,276,800
    char* ws = (char*)d_ws;
    bf16* Qb = (bf16*)(ws);
    bf16* Kb = (bf16*)(ws + (size_t)12582912);
    bf16* Vg = (bf16*)(ws + (size_t)25165824);
    bf16* Cc = (bf16*)(ws + (size_t)35651584);
    bf16* Wcat = (bf16*)(ws + (size_t)35651584);
    bf16* Wb = (bf16*)(ws + (size_t)46137344);

    cvt_all_kernel<<<dim3(3040), 256, 0, stream>>>(Wq, Wk, Wv, Wcat, Wo, Wb);
    qkv_kernel<<<dim3(BATCH * SEQ / 128, NUM_HEADS), 256, 0, stream>>>(
        src, bq, bk, bv, Wcat, Qb, Kb, Vg);
    attn_kernel<<<dim3(BH, SEQ / 64), 128, 0, stream>>>(Qb, Kb, Vg, Cc);
    proj_kernel<<<dim3(SEQ * BATCH / 128, D_MODEL / 128), 256, 0, stream>>>(
        Cc, Wb, bo, out);
}

// Round 7
// 186.771 us; speedup vs baseline: 1.1062x; 1.1062x over previous
//
#include <hip/hip_runtime.h>
#include <hip/hip_bf16.h>

#define D_MODEL 1280
#define NUM_HEADS 16
#define D_K 80
#define DP 96            // head dim padded to 3*32 for MFMA K-steps
#define SEQ 1024
#define BATCH 4
#define BH (BATCH*NUM_HEADS)

typedef __hip_bfloat16 bf16;
typedef short short8 __attribute__((ext_vector_type(8)));
typedef short short4v __attribute__((ext_vector_type(4)));
typedef float f32x4 __attribute__((ext_vector_type(4)));

__device__ __forceinline__ float b2f(bf16 x) { return __bfloat162float(x); }
__device__ __forceinline__ bf16 f2b(float x) { return __float2bfloat16(x); }
__device__ __forceinline__ short bbits(float x) {
    union { bf16 b; short s; } u; u.b = __float2bfloat16(x); return u.s;
}

#define MFMA16(a, b, c) __builtin_amdgcn_mfma_f32_16x16x32_bf16(a, b, c, 0, 0, 0)

// ---------------------------------------------------------------------------
// Kernel 0 (merged): pack Wq|Wk|Wv -> Wcat[h][240][96] bf16 with the
// channel-shuffle permutation folded into the K(input)-dim. Also Wo -> bf16.
// ---------------------------------------------------------------------------
__global__ __launch_bounds__(256) void cvt_all_kernel(
    const float* __restrict__ Wq, const float* __restrict__ Wk,
    const float* __restrict__ Wv, bf16* __restrict__ Wcat,
    const float* __restrict__ Wo, bf16* __restrict__ Wb)
{
    if (blockIdx.x < 1440) {
        int idx = blockIdx.x * 256 + threadIdx.x;
        int col = idx % 96;
        int row = (idx / 96) % 240;
        int h   = idx / (96 * 240);
        int mat = row / 80, e = row % 80;
        int c = col >> 4, j = col & 15;          // e' = c*16 + j
        const float* W = (mat == 0) ? Wq : (mat == 1) ? Wk : Wv;
        float v = (col < 80) ? W[(size_t)(h * 80 + e) * 80 + (j * 5 + c)] : 0.f;
        Wcat[idx] = f2b(v);
    } else {
        int idx = ((blockIdx.x - 1440) * 256 + threadIdx.x) * 4;
        float4 v = *(const float4*)(Wo + idx);
        Wb[idx]     = f2b(v.x);
        Wb[idx + 1] = f2b(v.y);
        Wb[idx + 2] = f2b(v.z);
        Wb[idx + 3] = f2b(v.w);
    }
}

// ---------------------------------------------------------------------------
// Kernel 1: per-head QKV projection via MFMA, register-direct X fragments.
// V tokens are stored in perm6 order within each 64-token tile:
// t=[js][m16][lq][r] -> p=[js][lq][m16][r], so attn's PV can consume P
// fragments lane-locally (no P LDS round-trip) while V matches the same
// contraction-index permutation.
// ---------------------------------------------------------------------------
__global__ __launch_bounds__(256) void qkv_kernel(
    const float* __restrict__ src,
    const float* __restrict__ bq, const float* __restrict__ bk,
    const float* __restrict__ bv, const bf16* __restrict__ Wcat,
    bf16* __restrict__ Qb, bf16* __restrict__ Kb, bf16* __restrict__ Vg)
{
    const int h = blockIdx.y;
    const int b = blockIdx.x >> 3;
    const int s0 = (blockIdx.x & 7) * 128;
    const int tid = threadIdx.x;
    const int wave = tid >> 6, lane = tid & 63;
    const int lquad = lane >> 4, lcol = lane & 15;
    const int bh = b * NUM_HEADS + h;

    // X fragments straight from global (permuted-K ordering)
    short8 xf[2][3];
    #pragma unroll
    for (int mt = 0; mt < 2; mt++)
        #pragma unroll
        for (int ks = 0; ks < 3; ks++) {
            const int c  = 2 * ks + (lquad >> 1);
            const int j0 = (lquad & 1) * 8;
            short8 t = {0, 0, 0, 0, 0, 0, 0, 0};
            if (c < 5) {   // c==5 is the zero pad (W pad cols are zero too)
                const float* p = src
                    + (size_t)(b * SEQ + s0 + wave * 32 + mt * 16 + lcol) * D_MODEL
                    + c * 256 + h * 16 + j0;
                float4 v0 = *(const float4*)p;
                float4 v1 = *(const float4*)(p + 4);
                t[0] = bbits(v0.x); t[1] = bbits(v0.y);
                t[2] = bbits(v0.z); t[3] = bbits(v0.w);
                t[4] = bbits(v1.x); t[5] = bbits(v1.y);
                t[6] = bbits(v1.z); t[7] = bbits(v1.w);
            }
            xf[mt][ks] = t;
        }

    const bf16* Wh = Wcat + (size_t)h * 240 * 96;
    const float qscale = 1.4426950408889634f * 0.11180339887498949f;
    const f32x4 fzero = {0.f, 0.f, 0.f, 0.f};

    // ---- Q and K: D[token][e] ----
    #pragma unroll
    for (int mat = 0; mat < 2; mat++) {
        const bf16* Wm = Wh + mat * 80 * 96;
        short8 wf[5][3];
        #pragma unroll
        for (int n = 0; n < 5; n++)
            #pragma unroll
            for (int ks = 0; ks < 3; ks++)
                wf[n][ks] = *(const short8*)(Wm + (n*16 + lcol)*96 + ks*32 + lquad*8);

        f32x4 acc[2][5];
        #pragma unroll
        for (int n = 0; n < 5; n++) {          // first ks folds zero-init
            acc[0][n] = MFMA16(xf[0][0], wf[n][0], fzero);
            acc[1][n] = MFMA16(xf[1][0], wf[n][0], fzero);
        }
        #pragma unroll
        for (int ks = 1; ks < 3; ks++)
            #pragma unroll
            for (int n = 0; n < 5; n++) {
                acc[0][n] = MFMA16(xf[0][ks], wf[n][ks], acc[0][n]);
                acc[1][n] = MFMA16(xf[1][ks], wf[n][ks], acc[1][n]);
            }

        const float* bias = (mat == 0) ? bq : bk;
        bf16* Out = (mat == 0) ? Qb : Kb;
        const float scale = (mat == 0) ? qscale : 1.f;
        #pragma unroll
        for (int n = 0; n < 5; n++) {
            float bb = bias[h * 80 + n * 16 + lcol];
            #pragma unroll
            for (int mt = 0; mt < 2; mt++)
                #pragma unroll
                for (int r = 0; r < 4; r++) {
                    int srow = s0 + wave*32 + mt*16 + lquad*4 + r;
                    Out[((size_t)bh * SEQ + srow) * DP + n*16 + lcol] =
                        f2b((acc[mt][n][r] + bb) * scale);
                }
        }
    }
    // zero pad e = 80..95 for Q and K (128 rows, 256 threads)
    {
        int i = tid >> 1, half = tid & 1;
        size_t row = ((size_t)bh * SEQ + s0 + i) * DP + 80 + half * 8;
        *(uint4*)(Qb + row) = make_uint4(0, 0, 0, 0);
        *(uint4*)(Kb + row) = make_uint4(0, 0, 0, 0);
    }

    // ---- V: D[e][perm6(token)] ----
    {
        const bf16* Wm = Wh + 2 * 80 * 96;
        short8 wf[5][3];
        #pragma unroll
        for (int m = 0; m < 5; m++)
            #pragma unroll
            for (int ks = 0; ks < 3; ks++)
                wf[m][ks] = *(const short8*)(Wm + (m*16 + lcol)*96 + ks*32 + lquad*8);

        f32x4 acc[5][2];
        #pragma unroll
        for (int m = 0; m < 5; m++) {          // first ks folds zero-init
            acc[m][0] = MFMA16(wf[m][0], xf[0][0], fzero);
            acc[m][1] = MFMA16(wf[m][0], xf[1][0], fzero);
        }
        #pragma unroll
        for (int ks = 1; ks < 3; ks++)
            #pragma unroll
            for (int m = 0; m < 5; m++) {
                acc[m][0] = MFMA16(wf[m][ks], xf[0][ks], acc[m][0]);
                acc[m][1] = MFMA16(wf[m][ks], xf[1][ks], acc[m][1]);
            }

        #pragma unroll
        for (int m = 0; m < 5; m++) {
            float4 bb4 = *(const float4*)(bv + h * 80 + m * 16 + lquad * 4);
            float bb[4] = {bb4.x, bb4.y, bb4.z, bb4.w};
            #pragma unroll
            for (int nt = 0; nt < 2; nt++)
                #pragma unroll
                for (int r = 0; r < 4; r++) {
                    int e = m*16 + lquad*4 + r;
                    int token = s0 + wave*32 + nt*16 + lcol;
                    int t6 = token & 63;
                    int pt = (t6 & 32) | ((t6 & 16) >> 2) | ((t6 & 12) << 1)
                           | (t6 & 3);
                    int ptok = (token & ~63) | pt;
                    Vg[((size_t)bh * D_K + e) * SEQ + ptok] =
                        f2b(acc[m][nt][r] + bb[r]);
                }
        }
    }
}

// ---------------------------------------------------------------------------
// Kernel 2: MFMA flash attention. Round-3 T14 schedule (K+V staged in LDS,
// scalar-reg prefetch, 2 waves, 4 blocks/CU) with the P LDS round-trip
// DELETED: P fragments built lane-locally from QK^T accumulators; V tokens
// pre-permuted (perm6, by qkv) so the MFMA contraction index matches.
// LDS 38,144 B: Qs 13312 | Ks 13312 | Vt 11520.
// ---------------------------------------------------------------------------
__global__ __launch_bounds__(128, 2) void attn_kernel(
    const bf16* __restrict__ Qb, const bf16* __restrict__ Kb,
    const bf16* __restrict__ Vg, bf16* __restrict__ Cc)
{
    __shared__ char smem[38144];
    bf16* Qs = (bf16*)smem;
    bf16* Ks = (bf16*)(smem + 13312);
    bf16* Vt = (bf16*)(smem + 26624);

    const int tid = threadIdx.x;
    const int wave = tid >> 6, lane = tid & 63;
    const int lquad = lane >> 4, lcol = lane & 15;
    const int bh = blockIdx.x;
    const int b = bh >> 4, h = bh & 15;
    const int q0 = blockIdx.y * 64;

    const uint4* Kg  = (const uint4*)(Kb + (size_t)bh * SEQ * DP);
    const bf16*  Vgb = Vg + (size_t)bh * D_K * SEQ;

    // staging maps as individual scalars (NO arrays -> no scratch demotion)
    const int i0 = tid, i1 = tid + 128, i2 = tid + 256,
              i3 = tid + 384, i4 = tid + 512, i5 = tid + 640;
    const int kd0 = (i0/12)*104 + (i0%12)*8, kd1 = (i1/12)*104 + (i1%12)*8,
              kd2 = (i2/12)*104 + (i2%12)*8, kd3 = (i3/12)*104 + (i3%12)*8,
              kd4 = (i4/12)*104 + (i4%12)*8, kd5 = (i5/12)*104 + (i5%12)*8;
    const int vd0 = (i0>>3)*72 + (i0&7)*8, vd1 = (i1>>3)*72 + (i1&7)*8,
              vd2 = (i2>>3)*72 + (i2&7)*8, vd3 = (i3>>3)*72 + (i3&7)*8,
              vd4 = (i4>>3)*72 + (i4&7)*8;
    const int vg0 = (i0>>3)*SEQ + (i0&7)*8, vg1 = (i1>>3)*SEQ + (i1&7)*8,
              vg2 = (i2>>3)*SEQ + (i2&7)*8, vg3 = (i3>>3)*SEQ + (i3&7)*8,
              vg4 = (i4>>3)*SEQ + (i4&7)*8;

    // stage Q tile: 64 x 96 -> row stride 104
    {
        const uint4* qg = (const uint4*)(Qb + ((size_t)bh * SEQ + q0) * DP);
        #pragma unroll
        for (int i = 0; i < 6; i++) {
            int idx = tid + i * 128, r = idx / 12, c = idx % 12;
            *(uint4*)(Qs + r * 104 + c * 8) = qg[idx];
        }
    }
    __syncthreads();

    short8 qf[2][3];
    #pragma unroll
    for (int nt = 0; nt < 2; nt++)
        #pragma unroll
        for (int ks = 0; ks < 3; ks++)
            qf[nt][ks] = *(const short8*)(Qs + (wave*32 + nt*16 + lcol)*104 + ks*32 + lquad*8);

    // stage tile 0 (Ks/Vt regions; does not touch Qs)
    *(uint4*)(Ks + kd0) = Kg[i0];
    *(uint4*)(Ks + kd1) = Kg[i1];
    *(uint4*)(Ks + kd2) = Kg[i2];
    *(uint4*)(Ks + kd3) = Kg[i3];
    *(uint4*)(Ks + kd4) = Kg[i4];
    *(uint4*)(Ks + kd5) = Kg[i5];
    *(uint4*)(Vt + vd0) = *(const uint4*)(Vgb + vg0);
    *(uint4*)(Vt + vd1) = *(const uint4*)(Vgb + vg1);
    *(uint4*)(Vt + vd2) = *(const uint4*)(Vgb + vg2);
    *(uint4*)(Vt + vd3) = *(const uint4*)(Vgb + vg3);
    *(uint4*)(Vt + vd4) = *(const uint4*)(Vgb + vg4);
    __syncthreads();

    f32x4 Oacc[2][5];
    #pragma unroll
    for (int mt = 0; mt < 2; mt++)
        #pragma unroll
        for (int ne = 0; ne < 5; ne++)
            #pragma unroll
            for (int r = 0; r < 4; r++) Oacc[mt][ne][r] = 0.f;

    f32x4 lsum4[2];
    #pragma unroll
    for (int nt = 0; nt < 2; nt++)
        #pragma unroll
        for (int r = 0; r < 4; r++) lsum4[nt][r] = 0.f;

    const f32x4 fzero = {0.f, 0.f, 0.f, 0.f};

    for (int kt = 0; kt < 16; kt++) {
        // T14: issue next tile's loads EARLY into scalar regs; straight-line
        const int ktn = (kt + 1) & 15;          // last iter republishes tile 0
        uint4 kA = Kg[ktn * 768 + i0];
        uint4 kB = Kg[ktn * 768 + i1];
        uint4 kC = Kg[ktn * 768 + i2];
        uint4 kD = Kg[ktn * 768 + i3];
        uint4 kE = Kg[ktn * 768 + i4];
        uint4 kF = Kg[ktn * 768 + i5];
        uint4 vA = *(const uint4*)(Vgb + vg0 + ktn * 64);
        uint4 vB = *(const uint4*)(Vgb + vg1 + ktn * 64);
        uint4 vC = *(const uint4*)(Vgb + vg2 + ktn * 64);
        uint4 vD = *(const uint4*)(Vgb + vg3 + ktn * 64);
        uint4 vE = *(const uint4*)(Vgb + vg4 + ktn * 64);

        // S^T = K·Q^T (first ks folds the zero-init)
        f32x4 st[4][2];
        __builtin_amdgcn_s_setprio(1);
        #pragma unroll
        for (int mt = 0; mt < 4; mt++) {
            short8 af = *(const short8*)(Ks + (mt*16 + lcol)*104 + lquad*8);
            st[mt][0] = MFMA16(af, qf[0][0], fzero);
            st[mt][1] = MFMA16(af, qf[1][0], fzero);
        }
        #pragma unroll
        for (int ks = 1; ks < 3; ks++)
            #pragma unroll
            for (int mt = 0; mt < 4; mt++) {
                short8 af = *(const short8*)(Ks + (mt*16 + lcol)*104 + ks*32 + lquad*8);
                st[mt][0] = MFMA16(af, qf[0][ks], st[mt][0]);
                st[mt][1] = MFMA16(af, qf[1][ks], st[mt][1]);
            }
        __builtin_amdgcn_s_setprio(0);

        // softmax numerator + PV, fused per js — P fragments are LANE-LOCAL:
        // pf[nt][js][j] = bf16(exp2(st[2js+(j>>2)][nt][j&3])); V was stored
        // perm6-permuted so the MFMA k-index matches on both operands.
        #pragma unroll
        for (int js = 0; js < 2; js++) {
            short8 pf0, pf1;
            #pragma unroll
            for (int half = 0; half < 2; half++)
                #pragma unroll
                for (int r = 0; r < 4; r++) {
                    float p0 = __builtin_amdgcn_exp2f(st[2*js+half][0][r]);
                    float p1 = __builtin_amdgcn_exp2f(st[2*js+half][1][r]);
                    lsum4[0][r] += p0;
                    lsum4[1][r] += p1;
                    pf0[half*4+r] = bbits(p0);
                    pf1[half*4+r] = bbits(p1);
                }
            __builtin_amdgcn_s_setprio(1);
            #pragma unroll
            for (int ne = 0; ne < 5; ne++) {
                short8 vfx = *(const short8*)(Vt + (ne*16 + lcol)*72 + js*32 + lquad*8);
                Oacc[0][ne] = MFMA16(pf0, vfx, Oacc[0][ne]);
                Oacc[1][ne] = MFMA16(pf1, vfx, Oacc[1][ne]);
            }
            __builtin_amdgcn_s_setprio(0);
        }

        // publish tile kt+1: only fast ds_writes between the barriers
        __syncthreads();
        *(uint4*)(Ks + kd0) = kA;
        *(uint4*)(Ks + kd1) = kB;
        *(uint4*)(Ks + kd2) = kC;
        *(uint4*)(Ks + kd3) = kD;
        *(uint4*)(Ks + kd4) = kE;
        *(uint4*)(Ks + kd5) = kF;
        *(uint4*)(Vt + vd0) = vA;
        *(uint4*)(Vt + vd1) = vB;
        *(uint4*)(Vt + vd2) = vC;
        *(uint4*)(Vt + vd3) = vD;
        *(uint4*)(Vt + vd4) = vE;
        __syncthreads();
    }

    // single l-reduce + normalize + write
    float inv[2];
    #pragma unroll
    for (int nt = 0; nt < 2; nt++) {
        float s = (lsum4[nt][0] + lsum4[nt][1]) + (lsum4[nt][2] + lsum4[nt][3]);
        s += __shfl_xor(s, 16);
        s += __shfl_xor(s, 32);
        inv[nt] = 1.f / s;
    }
    #pragma unroll
    for (int mt = 0; mt < 2; mt++) {
        f32x4 li;
        #pragma unroll
        for (int r = 0; r < 4; r++)
            li[r] = __shfl(inv[mt], (lane & 48) | (lquad*4 + r));
        #pragma unroll
        for (int ne = 0; ne < 5; ne++)
            #pragma unroll
            for (int r = 0; r < 4; r++) {
                int s_row = q0 + wave*32 + mt*16 + lquad*4 + r;
                int e = ne*16 + lcol;
                Cc[(size_t)(b * SEQ + s_row) * D_MODEL + h * D_K + e] =
                    f2b(Oacc[mt][ne][r] * li[r]);
            }
    }
}

// ---------------------------------------------------------------------------
// Kernel 3: output projection out = Cc @ Wo^T + bo via MFMA (unchanged r4).
// ---------------------------------------------------------------------------
__global__ __launch_bounds__(256) void proj_kernel(
    const bf16* __restrict__ Cc, const bf16* __restrict__ Wb,
    const float* __restrict__ bo, float* __restrict__ out)
{
    __shared__ bf16 As[128 * 72];
    __shared__ bf16 Bs[128 * 72];
    const int tid = threadIdx.x;
    const int wave = tid >> 6, lane = tid & 63;
    const int lquad = lane >> 4, lcol = lane & 15;
    const int t0 = blockIdx.x * 128, o0 = blockIdx.y * 128;
    const int mrow = (wave & 1) * 64, ncol = (wave >> 1) * 64;

    // staging maps as individual scalars
    const int i0 = tid, i1 = tid + 256, i2 = tid + 512, i3 = tid + 768;
    const int d0 = (i0>>3)*72 + (i0&7)*8, d1 = (i1>>3)*72 + (i1&7)*8,
              d2 = (i2>>3)*72 + (i2&7)*8, d3 = (i3>>3)*72 + (i3&7)*8;
    const size_t gA0 = (size_t)(t0 + (i0>>3))*D_MODEL + (i0&7)*8;
    const size_t gA1 = (size_t)(t0 + (i1>>3))*D_MODEL + (i1&7)*8;
    const size_t gA2 = (size_t)(t0 + (i2>>3))*D_MODEL + (i2&7)*8;
    const size_t gA3 = (size_t)(t0 + (i3>>3))*D_MODEL + (i3&7)*8;
    const size_t gB0 = (size_t)(o0 + (i0>>3))*D_MODEL + (i0&7)*8;
    const size_t gB1 = (size_t)(o0 + (i1>>3))*D_MODEL + (i1&7)*8;
    const size_t gB2 = (size_t)(o0 + (i2>>3))*D_MODEL + (i2&7)*8;
    const size_t gB3 = (size_t)(o0 + (i3>>3))*D_MODEL + (i3&7)*8;

    // stage K-chunk 0
    *(uint4*)(As + d0) = *(const uint4*)(Cc + gA0);
    *(uint4*)(As + d1) = *(const uint4*)(Cc + gA1);
    *(uint4*)(As + d2) = *(const uint4*)(Cc + gA2);
    *(uint4*)(As + d3) = *(const uint4*)(Cc + gA3);
    *(uint4*)(Bs + d0) = *(const uint4*)(Wb + gB0);
    *(uint4*)(Bs + d1) = *(const uint4*)(Wb + gB1);
    *(uint4*)(Bs + d2) = *(const uint4*)(Wb + gB2);
    *(uint4*)(Bs + d3) = *(const uint4*)(Wb + gB3);
    __syncthreads();

    f32x4 acc[4][4];
    #pragma unroll
    for (int mt = 0; mt < 4; mt++)
        #pragma unroll
        for (int nt = 0; nt < 4; nt++)
            #pragma unroll
            for (int r = 0; r < 4; r++) acc[mt][nt][r] = 0.f;

    for (int kc = 0; kc < 20; kc++) {
        // T14: prefetch next K-chunk into scalar regs (wraps to 0 at end)
        const int kn = (kc < 19) ? (kc + 1) * 64 : 0;
        uint4 pa0 = *(const uint4*)(Cc + gA0 + kn);
        uint4 pa1 = *(const uint4*)(Cc + gA1 + kn);
        uint4 pa2 = *(const uint4*)(Cc + gA2 + kn);
        uint4 pa3 = *(const uint4*)(Cc + gA3 + kn);
        uint4 pb0 = *(const uint4*)(Wb + gB0 + kn);
        uint4 pb1 = *(const uint4*)(Wb + gB1 + kn);
        uint4 pb2 = *(const uint4*)(Wb + gB2 + kn);
        uint4 pb3 = *(const uint4*)(Wb + gB3 + kn);

        __builtin_amdgcn_s_setprio(1);
        #pragma unroll
        for (int ks = 0; ks < 2; ks++) {
            short8 am[4], bn[4];
            #pragma unroll
            for (int t = 0; t < 4; t++) {
                am[t] = *(const short8*)(As + (mrow + t*16 + lcol)*72 + ks*32 + lquad*8);
                bn[t] = *(const short8*)(Bs + (ncol + t*16 + lcol)*72 + ks*32 + lquad*8);
            }
            #pragma unroll
            for (int mt = 0; mt < 4; mt++)
                #pragma unroll
                for (int nt = 0; nt < 4; nt++)
                    acc[mt][nt] = MFMA16(am[mt], bn[nt], acc[mt][nt]);
        }
        __builtin_amdgcn_s_setprio(0);

        // publish: only fast ds_writes between the barriers
        __syncthreads();
        *(uint4*)(As + d0) = pa0;
        *(uint4*)(As + d1) = pa1;
        *(uint4*)(As + d2) = pa2;
        *(uint4*)(As + d3) = pa3;
        *(uint4*)(Bs + d0) = pb0;
        *(uint4*)(Bs + d1) = pb1;
        *(uint4*)(Bs + d2) = pb2;
        *(uint4*)(Bs + d3) = pb3;
        __syncthreads();
    }

    #pragma unroll
    for (int nt = 0; nt < 4; nt++) {
        float bias = bo[o0 + ncol + nt*16 + lcol];
        #pragma unroll
        for (int mt = 0; mt < 4; mt++)
            #pragma unroll
            for (int r = 0; r < 4; r++)
                out[(size_t)(t0 + mrow + mt*16 + lquad*4 + r) * D_MODEL
                    + o0 + ncol + nt*16 + lcol] = acc[mt][nt][r] + bias;
    }
}

// ---------------------------------------------------------------------------
extern "C" void kernel_launch(void* const* d_in, const int* in_sizes, int n_in,
                              void* d_out, int out_size, void* d_ws, size_t ws_size,
                              hipStream_t stream) {
    const float* src = (const float*)d_in[0];
    const float* Wq = (const float*)d_in[3];
    const float* bq = (const float*)d_in[4];
    const float* Wk = (const float*)d_in[5];
    const float* bk = (const float*)d_in[6];
    const float* Wv = (const float*)d_in[7];
    const float* bv = (const float*)d_in[8];
    const float* Wo = (const float*)d_in[9];
    const float* bo = (const float*)d_in[10];
    float* out = (float*)d_out;

    // ws layout (bytes):
    //   Qb bf16 [BH][S][96]    @ 0         12,582,912
    //   Kb bf16 [BH][S][96]    @ 12582912  12,582,912
    //   Vg bf16 [BH][80][S]    @ 25165824  10,485,760  (perm6 token order)
    //   Cc bf16 [B][S][1280]   @ 35651584  10,485,760  (also Wcat before attn)
    //   Wb bf16 [1280][1280]   @ 46137344   3,276,800
    char* ws = (char*)d_ws;
    bf16* Qb = (bf16*)(ws);
    bf16* Kb = (bf16*)(ws + (size_t)12582912);
    bf16* Vg = (bf16*)(ws + (size_t)25165824);
    bf16* Cc = (bf16*)(ws + (size_t)35651584);
    bf16* Wcat = (bf16*)(ws + (size_t)35651584);
    bf16* Wb = (bf16*)(ws + (size_t)46137344);

    cvt_all_kernel<<<dim3(3040), 256, 0, stream>>>(Wq, Wk, Wv, Wcat, Wo, Wb);
    qkv_kernel<<<dim3(BATCH * SEQ / 128, NUM_HEADS), 256, 0, stream>>>(
        src, bq, bk, bv, Wcat, Qb, Kb, Vg);
    attn_kernel<<<dim3(BH, SEQ / 64), 128, 0, stream>>>(Qb, Kb, Vg, Cc);
    proj_kernel<<<dim3(SEQ * BATCH / 128, D_MODEL / 128), 256, 0, stream>>>(
        Cc, Wb, bo, out);
}